// Round 16
// baseline (630.359 us; speedup 1.0000x reference)
//
#include <hip/hip_runtime.h>
#include <math.h>

namespace {

typedef unsigned short u16;
typedef short bf16x8 __attribute__((ext_vector_type(8)));
typedef float f32x4 __attribute__((ext_vector_type(4)));

constexpr int B = 16, E = 2000, F = 8000, Q = 20, D = 100, NLAYER = 3;
constexpr int NUM_ENTITY_C = 500000;
constexpr int NREL1 = 6001;          // NUM_RELATION + 1
constexpr int SK = 128;              // bf16 activation row stride (K padded)
constexpr int WFSZ = 28 * 64 * 8;    // u16 per prepped weight matrix (14336)
constexpr int SST = 120;             // stage stride (u16)
constexpr float PAGERANK_LAMBDA = 0.8f;
constexpr float FACT_SCALE = 3.0f;
constexpr float VERY_NEG = -100000000000.0f;
constexpr float VERY_SMALL = 1e-10f;

__device__ __forceinline__ float sigf(float x) { return 1.0f / (1.0f + __expf(-x)); }

__device__ __forceinline__ short f2bf(float f) {
    union { float f; unsigned int u; } c; c.f = f;
    unsigned int u = c.u + 0x7FFF + ((c.u >> 16) & 1);   // RNE
    return (short)(u >> 16);
}
__device__ __forceinline__ float bf2f(u16 s) {
    union { unsigned int u; float f; } c; c.u = ((unsigned int)s) << 16;
    return c.f;
}

// ================= weight frag prep =================
__global__ void wprep_kernel(const float* __restrict__ rel_lin_w,
                             const float* __restrict__ self_w, const float* __restrict__ head_w,
                             const float* __restrict__ tail_w, const float* __restrict__ e2e_w,
                             u16* __restrict__ WF)
{
    int m = blockIdx.y;
    int ns = blockIdx.x;                 // n*4+s
    int n = ns >> 2, s = ns & 3;
    int lane = threadIdx.x;              // 64
    const float* W; int ldW = D, kofs = 0; float scale = 1.f;
    if (m == 0) { W = rel_lin_w; }
    else {
        int L = (m - 1) / 5, t = (m - 1) % 5;
        if (t == 0)      { W = self_w + (size_t)L * D * D; }
        else if (t == 1) { W = head_w + (size_t)L * D * D; }
        else if (t == 2) { W = tail_w + (size_t)L * D * D; scale = FACT_SCALE; }
        else if (t == 3) { W = e2e_w + (size_t)L * D * 3 * D; ldW = 3 * D; }
        else             { W = e2e_w + (size_t)L * D * 3 * D; ldW = 3 * D; kofs = 2 * D; }
    }
    int col = n * 16 + (lane & 15);
    int kb = s * 32 + (lane >> 4) * 8;
    bf16x8 f;
#pragma unroll
    for (int j = 0; j < 8; ++j) {
        int k = kb + j;
        float v = (col < D && k < D) ? scale * W[(size_t)col * ldW + kofs + k] : 0.f;
        f[j] = f2bf(v);
    }
    *reinterpret_cast<bf16x8*>(WF + ((size_t)m * 28 + ns) * 64 * 8 + lane * 8) = f;
}

// q_hidden -> B-operand fragments: qhB[b][n*4+s][lane][8]
__global__ void qhprep_kernel(const float* __restrict__ qh, u16* __restrict__ qhB)
{
    int b = blockIdx.x;
    int t = threadIdx.x;     // 512
    int ns = t >> 6;
    int lane = t & 63;
    int n = ns >> 2, s = ns & 3;
    int q = n * 16 + (lane & 15);
    int kb = s * 32 + (lane >> 4) * 8;
    bf16x8 f;
#pragma unroll
    for (int j = 0; j < 8; ++j) {
        int k = kb + j;
        float v = (q < Q && k < D) ? qh[((size_t)b * Q + q) * D + k] : 0.f;
        f[j] = f2bf(v);
    }
    *reinterpret_cast<bf16x8*>(qhB + ((size_t)(b * 8 + ns) * 64 + lane) * 8) = f;
}

// ========== MFMA Wf: sim -> softmax(q) -> wt=exp(Wf) + e2fsm atomic ==========
__global__ __launch_bounds__(256, 2) void wfm_kernel(const u16* __restrict__ REL,
                                                     const int* __restrict__ frel,
                                                     const u16* __restrict__ qhB,
                                                     const int* __restrict__ headAbs,
                                                     float* __restrict__ wt,
                                                     float* __restrict__ e2fsm, int nrows)
{
    const int lane = threadIdx.x & 63;
    const int lrow = lane & 15, lkg = lane >> 4;
    const int wv = blockIdx.x * (blockDim.x >> 6) + (threadIdx.x >> 6);
    const int nwv = gridDim.x * (blockDim.x >> 6);
    const int nch = nrows >> 4;

    for (int chunk = wv; chunk < nch; chunk += nwv) {
        const int row = chunk * 16 + lrow;
        const int b = (chunk * 16) / F;
        bf16x8 af[4];
        {
            const u16* src = REL + (size_t)frel[row] * SK;
#pragma unroll
            for (int s = 0; s < 4; ++s)
                af[s] = *reinterpret_cast<const bf16x8*>(src + s * 32 + lkg * 8);
        }
        f32x4 acc[2];
        acc[0] = (f32x4){0.f, 0.f, 0.f, 0.f};
        acc[1] = (f32x4){0.f, 0.f, 0.f, 0.f};
#pragma unroll
        for (int s = 0; s < 4; ++s) {
#pragma unroll
            for (int n = 0; n < 2; ++n) {
                bf16x8 qb = *reinterpret_cast<const bf16x8*>(
                    qhB + ((size_t)(b * 8 + n * 4 + s) * 64 + lane) * 8);
                acc[n] = __builtin_amdgcn_mfma_f32_16x16x32_bf16(af[s], qb, acc[n], 0, 0, 0);
            }
        }
        const bool v1 = lrow < (Q - 16);
#pragma unroll
        for (int r = 0; r < 4; ++r) {
            float s0 = acc[0][r] * 0.1f;
            float s1 = acc[1][r] * 0.1f;
            float m = v1 ? fmaxf(s0, s1) : s0;
#pragma unroll
            for (int d = 1; d < 16; d <<= 1) m = fmaxf(m, __shfl_xor(m, d));
            float e0 = __expf(s0 - m);
            float e1 = v1 ? __expf(s1 - m) : 0.f;
            float sum = e0 + e1;
            float wsum = fmaf(e0, s0, e1 * s1);
#pragma unroll
            for (int d = 1; d < 16; d <<= 1) {
                sum += __shfl_xor(sum, d);
                wsum += __shfl_xor(wsum, d);
            }
            if (lrow == 0) {
                int orow = chunk * 16 + lkg * 4 + r;
                float wtl = __expf(wsum / sum);      // no max-shift: cancels in wt/e2fsm
                wt[orow] = wtl;
                atomicAdd(&e2fsm[headAbs[orow]], wtl);
            }
        }
    }
}

// ====== HEAD-SORTED double mm: sequential embO reads, scattered row writes ======
// position i (head-sorted): e2f = relu(REL[hrel[i]]@self^T + embO[hhead[i]]@head^T + b1+b2)
//                                  * hrsv[i] * prO[hhead[i]]  -> row houtpos[i] (tail slot)
// hhead is non-decreasing within an XCD group (2 batches) -> embO reads sequential w/ reuse.
__global__ __launch_bounds__(256, 2) void mm2pipeH(
    const u16* __restrict__ RELp, const int* __restrict__ hrel,
    const u16* __restrict__ embp, const int* __restrict__ hhead,
    const int* __restrict__ houtpos,
    const u16* __restrict__ WF1, const u16* __restrict__ WF2,
    const float* __restrict__ b1, const float* __restrict__ b2,
    const float* __restrict__ hrsv, const float* __restrict__ prv,
    u16* __restrict__ outp, int nrows)
{
    __shared__ __align__(16) u16 stage[4][16][SST];
    __shared__ int opos[4][16];
    const int lane = threadIdx.x & 63;
    const int lrow = lane & 15, lkg = lane >> 4;
    const int wslot = threadIdx.x >> 6;
    const int nch = (nrows + 15) >> 4;

    // XCD partition: 512 blocks -> 8 groups x 64 blocks; group g owns [g*nchg,(g+1)*nchg)
    const int g = blockIdx.x & 7;
    const int lb = blockIdx.x >> 3;
    const int nchg = nch >> 3;
    const int cbase = g * nchg;
    const int wvg = lb * 4 + wslot;
    const int nwvg = 64 * 4;

    bf16x8 w1[7][4];
#pragma unroll
    for (int n = 0; n < 7; ++n)
#pragma unroll
        for (int s = 0; s < 4; ++s)
            w1[n][s] = *reinterpret_cast<const bf16x8*>(WF1 + ((size_t)(n * 4 + s) * 64 + lane) * 8);

    auto loadA = [&](int ch, bf16x8* f1, bf16x8* f2) {
        int row = ch * 16 + lrow;
        int ar = row < nrows ? row : nrows - 1;
        const u16* s1p = RELp + (size_t)hrel[ar] * SK;
        const u16* s2p = embp + (size_t)hhead[ar] * SK;
#pragma unroll
        for (int s = 0; s < 4; ++s) {
            f1[s] = *reinterpret_cast<const bf16x8*>(s1p + s * 32 + lkg * 8);
            f2[s] = *reinterpret_cast<const bf16x8*>(s2p + s * 32 + lkg * 8);
        }
    };

    int chunk = cbase + wvg;
    const int cend = cbase + nchg;
    if (chunk >= cend) return;
    bf16x8 cf1[4], cf2[4];
    loadA(chunk, cf1, cf2);
    while (true) {
        const int nxt = chunk + nwvg;
        const bool more = nxt < cend;
        bf16x8 nf1[4], nf2[4];
        if (more) loadA(nxt, nf1, nf2);   // prefetch overlaps MFMA+epilogue below

        f32x4 acc[7];
#pragma unroll
        for (int n = 0; n < 7; ++n) acc[n] = (f32x4){0.f, 0.f, 0.f, 0.f};
#pragma unroll
        for (int s = 0; s < 4; ++s) {
#pragma unroll
            for (int n = 0; n < 7; ++n)
                acc[n] = __builtin_amdgcn_mfma_f32_16x16x32_bf16(cf1[s], w1[n][s], acc[n], 0, 0, 0);
#pragma unroll
            for (int n = 0; n < 7; ++n) {
                bf16x8 w2 = *reinterpret_cast<const bf16x8*>(
                    WF2 + ((size_t)(n * 4 + s) * 64 + lane) * 8);
                acc[n] = __builtin_amdgcn_mfma_f32_16x16x32_bf16(cf2[s], w2, acc[n], 0, 0, 0);
            }
        }

        // epilogue: +b1+b2, relu, *hrsv[i]*prv[hhead[i]] ; stage + scattered row stores
        const int rb = chunk * 16 + lkg * 4;
#pragma unroll
        for (int r = 0; r < 4; ++r) {
            const int irow = rb + r;
            const int grow = irow < nrows ? irow : nrows - 1;
            const float rsv = hrsv[grow] * prv[hhead[grow]];
#pragma unroll
            for (int n = 0; n < 7; ++n) {
                const int col = n * 16 + lrow;
                float v = 0.f;
                if (col < D) {
                    v = acc[n][r] + b1[col] + b2[col];
                    v = fmaxf(v, 0.f) * rsv;
                }
                stage[wslot][lkg * 4 + r][col] = (u16)f2bf(v);
            }
            if (lrow == 0) opos[wslot][lkg * 4 + r] = (irow < nrows) ? houtpos[irow] : -1;
        }
#pragma unroll
        for (int idx = lane; idx < 16 * 13; idx += 64) {
            int rr = idx / 13, cc = idx - rr * 13;
            int orow = opos[wslot][rr];
            bf16x8 v = *reinterpret_cast<const bf16x8*>(&stage[wslot][rr][cc * 8]);
            if (orow >= 0)
                *reinterpret_cast<bf16x8*>(outp + (size_t)orow * SK + cc * 8) = v;
        }

        if (!more) break;
#pragma unroll
        for (int s = 0; s < 4; ++s) { cf1[s] = nf1[s]; cf2[s] = nf2[s]; }
        chunk = nxt;
    }
}

// ================= two-source MFMA row matmul (round-9 baseline) =================
// A1S: 0 bf16 dense SK, 2 f32 dense lda1
// A2S: 0 none, 2 CSR-range sum, 3 bf16 dense
// EPI: 0 plain+b1 ; 2 f2e ; 3 final-emb ; 4 final-score (b2=score_w, prOld=score_b, sheadv=local_entity)
// PR: fused pagerank (A2S==2 only)
template<int A1S, int A2S, int EPI, bool OUTBF, bool PR>
__global__ __launch_bounds__(256, 2) void mm2(
    const void* __restrict__ A1p, int lda1,
    const void* __restrict__ A2p,
    const u16* __restrict__ WF1, const u16* __restrict__ WF2,
    const float* __restrict__ b1, const float* __restrict__ b2,
    const float* __restrict__ vq,
    const int* __restrict__ row_start,
    const float* __restrict__ prOld, const int* __restrict__ sheadv,
    float* __restrict__ prNew,
    void* __restrict__ outp, int nrows)
{
    __shared__ __align__(16) u16 stage[4][16][SST];
    const int lane = threadIdx.x & 63;
    const int lrow = lane & 15, lkg = lane >> 4;
    const int wslot = threadIdx.x >> 6;
    const int wv = blockIdx.x * (blockDim.x >> 6) + wslot;
    const int nwv = gridDim.x * (blockDim.x >> 6);
    const int nch = (nrows + 15) >> 4;

    bf16x8 w1[7][4];
#pragma unroll
    for (int n = 0; n < 7; ++n)
#pragma unroll
        for (int s = 0; s < 4; ++s)
            w1[n][s] = *reinterpret_cast<const bf16x8*>(WF1 + ((size_t)(n * 4 + s) * 64 + lane) * 8);

    for (int chunk = wv; chunk < nch; chunk += nwv) {
        const int row = chunk * 16 + lrow;
        const int ar = row < nrows ? row : nrows - 1;

        // ---- A1 fragments ----
        bf16x8 af1[4];
        if (A1S == 0) {
            const u16* src = (const u16*)A1p + (size_t)ar * SK;
#pragma unroll
            for (int s = 0; s < 4; ++s)
                af1[s] = *reinterpret_cast<const bf16x8*>(src + s * 32 + lkg * 8);
        } else {
            const float* arow = (const float*)A1p + (size_t)ar * lda1;
#pragma unroll
            for (int s = 0; s < 4; ++s) {
                const int k0 = s * 32 + lkg * 8;
                float tv[8];
                if (k0 + 8 <= D) {
                    float4 v0 = *reinterpret_cast<const float4*>(arow + k0);
                    float4 v1 = *reinterpret_cast<const float4*>(arow + k0 + 4);
                    tv[0]=v0.x; tv[1]=v0.y; tv[2]=v0.z; tv[3]=v0.w;
                    tv[4]=v1.x; tv[5]=v1.y; tv[6]=v1.z; tv[7]=v1.w;
                } else {
#pragma unroll
                    for (int j = 0; j < 8; ++j) tv[j] = (k0 + j < D) ? arow[k0 + j] : 0.f;
                }
                bf16x8 f;
#pragma unroll
                for (int j = 0; j < 8; ++j) f[j] = f2bf(tv[j]);
                af1[s] = f;
            }
        }

        int s0 = 0, s1 = 0;
        if (A2S == 2) { s0 = row_start[ar]; s1 = row_start[ar + 1]; }

        bf16x8 af2[4];
        if (A2S == 3) {
            const u16* src = (const u16*)A2p + (size_t)ar * SK;
#pragma unroll
            for (int s = 0; s < 4; ++s)
                af2[s] = *reinterpret_cast<const bf16x8*>(src + s * 32 + lkg * 8);
        }

        f32x4 acc[7];
#pragma unroll
        for (int n = 0; n < 7; ++n) acc[n] = (f32x4){0.f, 0.f, 0.f, 0.f};
#pragma unroll
        for (int s = 0; s < 4; ++s) {
#pragma unroll
            for (int n = 0; n < 7; ++n)
                acc[n] = __builtin_amdgcn_mfma_f32_16x16x32_bf16(af1[s], w1[n][s], acc[n], 0, 0, 0);
            if (A2S == 3) {
#pragma unroll
                for (int n = 0; n < 7; ++n) {
                    bf16x8 w2 = *reinterpret_cast<const bf16x8*>(
                        WF2 + ((size_t)(n * 4 + s) * 64 + lane) * 8);
                    acc[n] = __builtin_amdgcn_mfma_f32_16x16x32_bf16(af2[s], w2, acc[n], 0, 0, 0);
                }
            } else if (A2S == 2) {
                float a2f[8];
#pragma unroll
                for (int j = 0; j < 8; ++j) a2f[j] = 0.f;
                for (int i = s0; i < s1; ++i) {   // contiguous (tail-sorted)
                    bf16x8 v = *reinterpret_cast<const bf16x8*>(
                        (const u16*)A2p + (size_t)i * SK + s * 32 + lkg * 8);
#pragma unroll
                    for (int j = 0; j < 8; ++j) a2f[j] += bf2f((u16)v[j]);
                }
                bf16x8 fsum;
#pragma unroll
                for (int j = 0; j < 8; ++j) fsum[j] = f2bf(a2f[j]);
#pragma unroll
                for (int n = 0; n < 7; ++n) {
                    bf16x8 w2 = *reinterpret_cast<const bf16x8*>(
                        WF2 + ((size_t)(n * 4 + s) * 64 + lane) * 8);
                    acc[n] = __builtin_amdgcn_mfma_f32_16x16x32_bf16(fsum, w2, acc[n], 0, 0, 0);
                }
            }
        }
        if (PR && A2S == 2) {
            if (lkg == 0 && row < nrows) {
                float a = 0.f;
                for (int i = s0; i < s1; ++i) a += prOld[sheadv[i]];
                prNew[row] = PAGERANK_LAMBDA * a + (1.0f - PAGERANK_LAMBDA) * prOld[row];
            }
        }

        // ---- epilogue ----  C/D: col = lane&15, row = (lane>>4)*4 + reg
        const int rb = chunk * 16 + lkg * 4;
        const int bb = (chunk * 16) / E;
#pragma unroll
        for (int r = 0; r < 4; ++r) {
            const int orow = rb + r;
            const int grow = orow < nrows ? orow : nrows - 1;
            float cntf = 0.f;
            if (EPI == 2) cntf = (float)(row_start[grow + 1] - row_start[grow]);
            float scr = 0.f;
#pragma unroll
            for (int n = 0; n < 7; ++n) {
                const int col = n * 16 + lrow;
                float v = 0.f;
                if (col < D) {
                    v = acc[n][r];
                    if (b1) v += b1[col];
                    if (EPI == 2) v += FACT_SCALE * cntf * b2[col];
                    if (EPI == 3 || EPI == 4) v += vq[bb * D + col];
                    if (EPI != 0) v = fmaxf(v, 0.f);
                }
                if (EPI == 4) {
                    if (col < D) scr = fmaf(v, b2[col], scr);
                } else if (OUTBF) {
                    stage[wslot][lkg * 4 + r][col] = (u16)f2bf(v);
                } else if (col < D && orow < nrows) {
                    ((float*)outp)[(size_t)orow * D + col] = v;
                }
            }
            if (EPI == 4) {
                scr += __shfl_xor(scr, 1);
                scr += __shfl_xor(scr, 2);
                scr += __shfl_xor(scr, 4);
                scr += __shfl_xor(scr, 8);
                if (lrow == 0 && orow < nrows) {
                    float s = scr + prOld[0] +
                              ((sheadv[orow] != NUM_ENTITY_C) ? 0.f : VERY_NEG);
                    ((float*)outp)[orow] = s;
                }
            }
        }
        if (OUTBF && EPI != 4) {
            // wave-internal LDS transpose -> wide 16B stores (13 x bf16x8 = cols 0..103)
#pragma unroll
            for (int idx = lane; idx < 16 * 13; idx += 64) {
                int rr = idx / 13, cc = idx - rr * 13;
                int orow = chunk * 16 + rr;
                bf16x8 v = *reinterpret_cast<const bf16x8*>(&stage[wslot][rr][cc * 8]);
                if (orow < nrows)
                    *reinterpret_cast<bf16x8*>((u16*)outp + (size_t)orow * SK + cc * 8) = v;
            }
        }
    }
}

// ================= LSTM =================
__global__ __launch_bounds__(512) void gatesx_kernel(
    const int* __restrict__ qtext, const float* __restrict__ wtab,
    const float* __restrict__ wih, const float* __restrict__ bih,
    const float* __restrict__ bhh, float* __restrict__ gx)
{
    int row = blockIdx.x;
    int t = threadIdx.x;
    __shared__ __align__(16) float xs[D];
    if (t < D) xs[t] = wtab[(size_t)qtext[row] * D + t];
    __syncthreads();
    if (t < 4 * D) {
        const float4* w4 = reinterpret_cast<const float4*>(wih + (size_t)t * D);
        const float4* x4 = reinterpret_cast<const float4*>(xs);
        float a0 = 0.f, a1 = 0.f, a2 = 0.f, a3 = 0.f;
#pragma unroll
        for (int k = 0; k < 25; ++k) {
            float4 wv = w4[k]; float4 xv = x4[k];
            a0 = fmaf(wv.x, xv.x, a0); a1 = fmaf(wv.y, xv.y, a1);
            a2 = fmaf(wv.z, xv.z, a2); a3 = fmaf(wv.w, xv.w, a3);
        }
        gx[(size_t)row * (4 * D) + t] = a0 + a1 + a2 + a3 + bih[t] + bhh[t];
    }
}

__global__ __launch_bounds__(512) void lstmrec_kernel(
    const float* __restrict__ gx, const float* __restrict__ whh,
    float* __restrict__ q_hidden, float* __restrict__ qne)
{
    int b = blockIdx.x, t = threadIdx.x;
    __shared__ __align__(16) float h[D];
    __shared__ float cst[D];
    __shared__ float g[4 * D];
    float4 w[25];
    if (t < 4 * D) {
        const float4* wr = reinterpret_cast<const float4*>(whh + (size_t)t * D);
#pragma unroll
        for (int k = 0; k < 25; ++k) w[k] = wr[k];
    }
    if (t < D) { h[t] = 0.f; cst[t] = 0.f; }
    __syncthreads();
    for (int step = 0; step < Q; ++step) {
        if (t < 4 * D) {
            const float4* h4 = reinterpret_cast<const float4*>(h);
            float a0 = 0.f, a1 = 0.f, a2 = 0.f, a3 = 0.f;
#pragma unroll
            for (int k = 0; k < 25; ++k) {
                float4 hv = h4[k];
                a0 = fmaf(w[k].x, hv.x, a0); a1 = fmaf(w[k].y, hv.y, a1);
                a2 = fmaf(w[k].z, hv.z, a2); a3 = fmaf(w[k].w, hv.w, a3);
            }
            g[t] = a0 + a1 + a2 + a3 + gx[((size_t)b * Q + step) * (4 * D) + t];
        }
        __syncthreads();
        if (t < D) {
            float gi = g[t], gf = g[t + D], gg = g[t + 2 * D], go = g[t + 3 * D];
            float cn = sigf(gf) * cst[t] + sigf(gi) * tanhf(gg);
            float hn = sigf(go) * tanhf(cn);
            cst[t] = cn; h[t] = hn;
            q_hidden[((size_t)b * Q + step) * D + t] = hn;
            if (step == Q - 1) qne[b * D + t] = hn;
        }
        __syncthreads();
    }
}

// ================= small helpers =================
__global__ void idxabs_kernel(const int* __restrict__ kb_head, const int* __restrict__ kb_tail,
                              int* __restrict__ headAbs, int* __restrict__ tailAbs,
                              int* __restrict__ counts, int* __restrict__ hcounts)
{
    int r = blockIdx.x * 256 + threadIdx.x;
    if (r < B * F) {
        int b = r / F;
        int h = b * E + kb_head[r];
        headAbs[r] = h;
        int t = b * E + kb_tail[r];
        tailAbs[r] = t;
        atomicAdd(&counts[t], 1);
        atomicAdd(&hcounts[h], 1);
    }
}

__global__ __launch_bounds__(1024) void scan_kernel(const int* __restrict__ counts,
                                                    int* __restrict__ row_start,
                                                    int* __restrict__ cursor)
{
    __shared__ int part[1024];
    int t = threadIdx.x;
    int base = t * 32;
    int local[32];
    int s = 0;
#pragma unroll
    for (int i = 0; i < 32; ++i) {
        int idx = base + i;
        int v = (idx < B * E) ? counts[idx] : 0;
        local[i] = s; s += v;
    }
    part[t] = s;
    __syncthreads();
    for (int off = 1; off < 1024; off <<= 1) {
        int v = (t >= off) ? part[t - off] : 0;
        __syncthreads();
        if (t >= off) part[t] += v;
        __syncthreads();
    }
    int prev = (t > 0) ? part[t - 1] : 0;
#pragma unroll
    for (int i = 0; i < 32; ++i) {
        int idx = base + i;
        if (idx < B * E) { int rs = prev + local[i]; row_start[idx] = rs; cursor[idx] = rs; }
    }
    if (t == 1023) row_start[B * E] = part[1023];
}

// tail fill (shead for pagerank) + head-sorted metadata for mm2pipeH
__global__ void fillsprep_kernel(const int* __restrict__ tailAbs, int* __restrict__ cursor,
                                 int* __restrict__ hcursor,
                                 const int* __restrict__ headAbs, const int* __restrict__ frel,
                                 const float* __restrict__ wt, const float* __restrict__ e2fsm,
                                 int* __restrict__ shead,
                                 int* __restrict__ hrel, int* __restrict__ hhead,
                                 float* __restrict__ hrsv, int* __restrict__ houtpos)
{
    int r = blockIdx.x * 256 + threadIdx.x;
    if (r < B * F) {
        int h = headAbs[r];
        int p = atomicAdd(&cursor[tailAbs[r]], 1);
        shead[p] = h;
        int p2 = atomicAdd(&hcursor[h], 1);
        hrel[p2] = frel[r];
        hhead[p2] = h;
        hrsv[p2] = wt[r] / fmaxf(e2fsm[h], VERY_SMALL);
        houtpos[p2] = p;
    }
}

__global__ void entgather_kernel(const int* __restrict__ local_entity,
                                 const float* __restrict__ etab, u16* __restrict__ emb,
                                 const float* __restrict__ q2e_adj, float* __restrict__ pr)
{
    int i = blockIdx.x * 256 + threadIdx.x;
    if (i < B * E) pr[i] = q2e_adj[i];
    if (i < B * E * 25) {
        int row = i / 25, p = i - row * 25;
        float4 v = reinterpret_cast<const float4*>(etab + (size_t)local_entity[row] * D)[p];
        short4 o;
        o.x = f2bf(v.x); o.y = f2bf(v.y); o.z = f2bf(v.z); o.w = f2bf(v.w);
        *reinterpret_cast<short4*>(emb + (size_t)row * SK + p * 4) = o;
    }
}

// [optional qne from z] -> q2e_vec -> vq ; clears z for next accumulation
template<bool HASQNE>
__global__ void qvec_kernel(const float* __restrict__ qneIn, float* __restrict__ z,
                            const float* __restrict__ e2qw, const float* __restrict__ e2qb,
                            const float* __restrict__ q2ew, const float* __restrict__ q2eb,
                            const float* __restrict__ e2ew,
                            float* __restrict__ q2e_vec, float* __restrict__ vq)
{
    int b = blockIdx.x, t = threadIdx.x;   // 128 threads
    __shared__ float qn[D];
    __shared__ float qv[D];
    __shared__ float zb[201];
    float* zg = z + b * 201;
    if (HASQNE) {
        for (int i = t; i < 201; i += 128) { zb[i] = zg[i]; zg[i] = 0.f; }
        __syncthreads();
        if (t < D) {
            float ps = zb[2 * D];
            const float* wr = e2qw + (size_t)t * 3 * D;
            float acc = ps * e2qb[t];
            for (int k = 0; k < D; ++k) {
                acc = fmaf(zb[k], wr[k], acc);
                acc = fmaf(ps * q2e_vec[b * D + k], wr[D + k], acc);
                acc = fmaf(zb[D + k], wr[2 * D + k], acc);
            }
            qn[t] = acc;
        }
    } else {
        for (int i = t; i < 201; i += 128) zg[i] = 0.f;
        if (t < D) qn[t] = qneIn[b * D + t];
    }
    __syncthreads();
    if (t < D) {
        const float* wr = q2ew + (size_t)t * D;
        float acc = q2eb[t];
        for (int k = 0; k < D; ++k) acc = fmaf(qn[k], wr[k], acc);
        qv[t] = acc;
    }
    __syncthreads();
    if (t < D) {
        q2e_vec[b * D + t] = qv[t];
        const float* wr = e2ew + (size_t)t * 300 + 100;
        float acc = 0.f;
        for (int k = 0; k < D; ++k) acc = fmaf(qv[k], wr[k], acc);
        vq[b * D + t] = acc;
    }
}

// z per b: [0..99]=sum p*emb, [100..199]=sum p*f2e, [200]=sum p  (atomics; z pre-cleared)
__global__ __launch_bounds__(256) void zsum_kernel(const float* __restrict__ pr,
                                                   const u16* __restrict__ emb,
                                                   const u16* __restrict__ f2e,
                                                   float* __restrict__ z)
{
    const int b = blockIdx.x, ch = blockIdx.y;
    const int t = threadIdx.x;
    const int g = t >> 4, tg = t & 15;
    const int ebase = ch * (E / 16);
    const int eend = ebase + (E / 16);
    float accA[8], accB[8];
#pragma unroll
    for (int j = 0; j < 8; ++j) { accA[j] = 0.f; accB[j] = 0.f; }
    float accp = 0.f;
    for (int e = ebase + g; e < eend; e += 16) {
        const float p = pr[b * E + e];
        const size_t ro = ((size_t)b * E + e) * SK + tg * 8;
        bf16x8 va = *reinterpret_cast<const bf16x8*>(emb + ro);
        bf16x8 vb = *reinterpret_cast<const bf16x8*>(f2e + ro);
#pragma unroll
        for (int j = 0; j < 8; ++j) {
            accA[j] = fmaf(p, bf2f((u16)va[j]), accA[j]);
            accB[j] = fmaf(p, bf2f((u16)vb[j]), accB[j]);
        }
        if (tg == 0) accp += p;
    }
    __shared__ float smA[16][132];
    __shared__ float smB[16][132];
    __shared__ float smp[16];
#pragma unroll
    for (int j = 0; j < 8; ++j) {
        smA[g][tg * 8 + j] = accA[j];
        smB[g][tg * 8 + j] = accB[j];
    }
    if (tg == 0) smp[g] = accp;
    __syncthreads();
    if (t < D) {
        float sa = 0.f, sb = 0.f;
#pragma unroll
        for (int gg = 0; gg < 16; ++gg) { sa += smA[gg][t]; sb += smB[gg][t]; }
        atomicAdd(&z[b * 201 + t], sa);
        atomicAdd(&z[b * 201 + D + t], sb);
    }
    if (t == 255) {
        float sp = 0.f;
#pragma unroll
        for (int gg = 0; gg < 16; ++gg) sp += smp[gg];
        atomicAdd(&z[b * 201 + 2 * D], sp);
    }
}

int mmgrid(int nrows) {      // 4 chunks/wave
    int ch = (nrows + 15) / 16;
    int blocks = (ch + 3) / 4;
    return blocks < 512 ? blocks : 512;
}
int mmgrid2(int nrows) {     // 2 chunks/wave, cap 1024
    int ch = (nrows + 15) / 16;
    int blocks = (ch + 7) / 8;
    return blocks < 1024 ? blocks : 1024;
}

}  // namespace

extern "C" void kernel_launch(void* const* d_in, const int* in_sizes, int n_in,
                              void* d_out, int out_size, void* d_ws, size_t ws_size,
                              hipStream_t stream)
{
    (void)in_sizes; (void)n_in; (void)out_size;
    const int*   local_entity = (const int*)d_in[0];
    const int*   kb_fact_rel  = (const int*)d_in[1];
    const int*   kb_head      = (const int*)d_in[2];
    const int*   kb_tail      = (const int*)d_in[3];
    const int*   query_text   = (const int*)d_in[4];
    const float* q2e_adj      = (const float*)d_in[5];
    const float* entity_table = (const float*)d_in[6];
    const float* rel_table    = (const float*)d_in[7];
    const float* word_table   = (const float*)d_in[8];
    const float* rel_lin_w    = (const float*)d_in[9];
    const float* rel_lin_b    = (const float*)d_in[10];
    const float* lstm_wih     = (const float*)d_in[11];
    const float* lstm_whh     = (const float*)d_in[12];
    const float* lstm_bih     = (const float*)d_in[13];
    const float* lstm_bhh     = (const float*)d_in[14];
    const float* q2e_w        = (const float*)d_in[15];
    const float* q2e_b        = (const float*)d_in[16];
    const float* e2q_w        = (const float*)d_in[17];
    const float* e2q_b        = (const float*)d_in[18];
    const float* e2e_w        = (const float*)d_in[19];
    const float* e2e_b        = (const float*)d_in[20];
    const float* head_w       = (const float*)d_in[21];
    const float* head_b       = (const float*)d_in[22];
    const float* tail_w       = (const float*)d_in[23];
    const float* tail_b       = (const float*)d_in[24];
    const float* self_w       = (const float*)d_in[25];
    const float* self_b       = (const float*)d_in[26];
    const float* score_w      = (const float*)d_in[27];
    const float* score_b      = (const float*)d_in[28];
    float* out = (float*)d_out;

    float* ws = (float*)d_ws;
    size_t o = 0;
    auto alloc = [&](size_t n) { float* p = ws + o; o += (n + 3) & ~(size_t)3; return p; };
    float* q_hidden = alloc((size_t)B * Q * D);
    float* qne      = alloc(B * D);
    float* gx       = alloc((size_t)B * Q * 4 * D);
    float* wt       = alloc((size_t)B * F);
    float* e2fsm    = alloc(B * E);      // e2fsm + counts + hcounts: single memset (3*B*E)
    int*   counts   = (int*)alloc(B * E);
    int*   hcounts  = (int*)alloc(B * E);
    float* pr0      = alloc(B * E);
    float* pr1      = alloc(B * E);
    float* q2e_vec  = alloc(B * D);
    float* vq       = alloc(B * D);
    float* z        = alloc(B * 201);
    float* hrsv     = alloc((size_t)B * F);
    u16* WF   = (u16*)alloc((size_t)16 * WFSZ / 2);
    u16* qhB  = (u16*)alloc((size_t)B * 8 * 64 * 8 / 2);
    u16* REL  = (u16*)alloc((size_t)NREL1 * SK / 2 + 64);
    u16* emb0 = (u16*)alloc((size_t)B * E * SK / 2);
    u16* emb1 = (u16*)alloc((size_t)B * E * SK / 2);
    u16* e2fS = (u16*)alloc((size_t)B * F * SK / 2);
    u16* f2e  = (u16*)alloc((size_t)B * E * SK / 2);
    int* headAbs  = (int*)alloc((size_t)B * F);
    int* tailAbs  = (int*)alloc((size_t)B * F);
    int* row_start= (int*)alloc(B * E + 1);
    int* hstart   = (int*)alloc(B * E + 1);
    int* cursor   = (int*)alloc(B * E);
    int* hcursor  = (int*)alloc(B * E);
    int* shead    = (int*)alloc((size_t)B * F);
    int* hrel     = (int*)alloc((size_t)B * F);
    int* hhead    = (int*)alloc((size_t)B * F);
    int* houtpos  = (int*)alloc((size_t)B * F);
    if (ws_size < o * sizeof(float)) return;

    auto WFm = [&](int m) { return WF + (size_t)m * WFSZ; };

    // ---- prep: weights, LSTM, CSRs, REL, attention ----
    wprep_kernel<<<dim3(28, 16), dim3(64), 0, stream>>>(rel_lin_w, self_w, head_w, tail_w,
                                                        e2e_w, WF);
    gatesx_kernel<<<dim3(B * Q), dim3(512), 0, stream>>>(query_text, word_table, lstm_wih,
                                                         lstm_bih, lstm_bhh, gx);
    lstmrec_kernel<<<dim3(B), dim3(512), 0, stream>>>(gx, lstm_whh, q_hidden, qne);
    qhprep_kernel<<<dim3(B), dim3(512), 0, stream>>>(q_hidden, qhB);
    hipMemsetAsync(e2fsm, 0, (size_t)3 * B * E * sizeof(float), stream);  // e2fsm+counts+hcounts
    idxabs_kernel<<<dim3((B * F + 255) / 256), dim3(256), 0, stream>>>(
        kb_head, kb_tail, headAbs, tailAbs, counts, hcounts);
    scan_kernel<<<dim3(1), dim3(1024), 0, stream>>>(counts, row_start, cursor);
    scan_kernel<<<dim3(1), dim3(1024), 0, stream>>>(hcounts, hstart, hcursor);
    mm2<2, 0, 0, true, false><<<dim3(mmgrid(NREL1)), dim3(256), 0, stream>>>(
        rel_table, D, nullptr, WFm(0), nullptr, rel_lin_b, nullptr,
        nullptr, nullptr, nullptr, nullptr, nullptr,
        REL, NREL1);
    wfm_kernel<<<dim3(mmgrid2(B * F)), dim3(256), 0, stream>>>(
        REL, kb_fact_rel, qhB, headAbs, wt, e2fsm, B * F);
    fillsprep_kernel<<<dim3((B * F + 255) / 256), dim3(256), 0, stream>>>(
        tailAbs, cursor, hcursor, headAbs, kb_fact_rel, wt, e2fsm,
        shead, hrel, hhead, hrsv, houtpos);
    entgather_kernel<<<dim3((B * E * 25 + 255) / 256), dim3(256), 0, stream>>>(
        local_entity, entity_table, emb0, q2e_adj, pr0);

    u16* embO = emb0; u16* embN = emb1;
    float* prO = pr0; float* prN = pr1;
    for (int i = 0; i < NLAYER; ++i) {
        const float* q2e_wi  = q2e_w + (size_t)i * D * D;
        const float* q2e_bi  = q2e_b + i * D;
        const float* e2e_wi  = e2e_w + (size_t)i * D * 3 * D;
        const float* e2e_bi  = e2e_b + i * D;
        const float* head_bi = head_b + i * D;
        const float* tail_bi = tail_b + i * D;
        const float* self_bi = self_b + i * D;
        const u16* wf_self = WFm(1 + i * 5 + 0);
        const u16* wf_head = WFm(1 + i * 5 + 1);
        const u16* wf_tail = WFm(1 + i * 5 + 2);
        const u16* wf_e2e0 = WFm(1 + i * 5 + 3);
        const u16* wf_e2e2 = WFm(1 + i * 5 + 4);
        const bool last = (i == NLAYER - 1);

        if (i == 0)
            qvec_kernel<false><<<dim3(B), dim3(128), 0, stream>>>(
                qne, z, nullptr, nullptr, q2e_wi, q2e_bi, e2e_wi, q2e_vec, vq);
        else
            qvec_kernel<true><<<dim3(B), dim3(128), 0, stream>>>(
                nullptr, z, e2q_w + (size_t)(i - 1) * D * 3 * D, e2q_b + (size_t)(i - 1) * D,
                q2e_wi, q2e_bi, e2e_wi, q2e_vec, vq);

        // e2fS: head-sorted traversal (sequential embO reads), scattered tail-slot writes
        mm2pipeH<<<dim3(512), dim3(256), 0, stream>>>(
            REL, hrel, embO, hhead, houtpos, wf_self, wf_head, self_bi, head_bi,
            hrsv, prO, e2fS, B * F);
        // f2e = relu(embO@self^T + b + FS*(rangesum(e2fS)@tail^T + cnt*b2)); prN fused (L1-2)
        if (!last)
            mm2<0, 2, 2, true, true><<<dim3(mmgrid(B * E)), dim3(256), 0, stream>>>(
                embO, 0, e2fS, wf_self, wf_tail, self_bi, tail_bi,
                nullptr, row_start, prO, shead, prN,
                f2e, B * E);
        else
            mm2<0, 2, 2, true, false><<<dim3(mmgrid(B * E)), dim3(256), 0, stream>>>(
                embO, 0, e2fS, wf_self, wf_tail, self_bi, tail_bi,
                nullptr, row_start, nullptr, nullptr, nullptr,
                f2e, B * E);
        if (!last)
            zsum_kernel<<<dim3(B, 16), dim3(256), 0, stream>>>(prN, embO, f2e, z);
        // final: embN (L1-2) or score directly (L3)
        if (!last)
            mm2<0, 3, 3, true, false><<<dim3(mmgrid(B * E)), dim3(256), 0, stream>>>(
                embO, 0, f2e, wf_e2e0, wf_e2e2, e2e_bi, nullptr,
                vq, nullptr, nullptr, nullptr, nullptr,
                embN, B * E);
        else
            mm2<0, 3, 4, false, false><<<dim3(mmgrid(B * E)), dim3(256), 0, stream>>>(
                embO, 0, f2e, wf_e2e0, wf_e2e2, e2e_bi, score_w,
                vq, nullptr, score_b, local_entity, nullptr,
                out, B * E);
        { u16* tmp = embO; embO = embN; embN = tmp; }
        { float* tmp = prO; prO = prN; prN = tmp; }
    }
}

// Round 17
// 558.373 us; speedup vs baseline: 1.1289x; 1.1289x over previous
//
#include <hip/hip_runtime.h>
#include <math.h>

namespace {

typedef unsigned short u16;
typedef short bf16x8 __attribute__((ext_vector_type(8)));
typedef float f32x4 __attribute__((ext_vector_type(4)));

constexpr int B = 16, E = 2000, F = 8000, Q = 20, D = 100, NLAYER = 3;
constexpr int NUM_ENTITY_C = 500000;
constexpr int NREL1 = 6001;          // NUM_RELATION + 1
constexpr int SK = 128;              // bf16 activation row stride (K padded)
constexpr int WFSZ = 28 * 64 * 8;    // u16 per prepped weight matrix (14336)
constexpr int SST = 120;             // stage stride (u16)
constexpr float PAGERANK_LAMBDA = 0.8f;
constexpr float FACT_SCALE = 3.0f;
constexpr float VERY_NEG = -100000000000.0f;
constexpr float VERY_SMALL = 1e-10f;

__device__ __forceinline__ float sigf(float x) { return 1.0f / (1.0f + __expf(-x)); }

__device__ __forceinline__ short f2bf(float f) {
    union { float f; unsigned int u; } c; c.f = f;
    unsigned int u = c.u + 0x7FFF + ((c.u >> 16) & 1);   // RNE
    return (short)(u >> 16);
}
__device__ __forceinline__ float bf2f(u16 s) {
    union { unsigned int u; float f; } c; c.u = ((unsigned int)s) << 16;
    return c.f;
}

// ================= weight frag prep =================
__global__ void wprep_kernel(const float* __restrict__ rel_lin_w,
                             const float* __restrict__ self_w, const float* __restrict__ head_w,
                             const float* __restrict__ tail_w, const float* __restrict__ e2e_w,
                             u16* __restrict__ WF)
{
    int m = blockIdx.y;
    int ns = blockIdx.x;                 // n*4+s
    int n = ns >> 2, s = ns & 3;
    int lane = threadIdx.x;              // 64
    const float* W; int ldW = D, kofs = 0; float scale = 1.f;
    if (m == 0) { W = rel_lin_w; }
    else {
        int L = (m - 1) / 5, t = (m - 1) % 5;
        if (t == 0)      { W = self_w + (size_t)L * D * D; }
        else if (t == 1) { W = head_w + (size_t)L * D * D; }
        else if (t == 2) { W = tail_w + (size_t)L * D * D; scale = FACT_SCALE; }
        else if (t == 3) { W = e2e_w + (size_t)L * D * 3 * D; ldW = 3 * D; }
        else             { W = e2e_w + (size_t)L * D * 3 * D; ldW = 3 * D; kofs = 2 * D; }
    }
    int col = n * 16 + (lane & 15);
    int kb = s * 32 + (lane >> 4) * 8;
    bf16x8 f;
#pragma unroll
    for (int j = 0; j < 8; ++j) {
        int k = kb + j;
        float v = (col < D && k < D) ? scale * W[(size_t)col * ldW + kofs + k] : 0.f;
        f[j] = f2bf(v);
    }
    *reinterpret_cast<bf16x8*>(WF + ((size_t)m * 28 + ns) * 64 * 8 + lane * 8) = f;
}

// q_hidden -> B-operand fragments: qhB[b][n*4+s][lane][8]
__global__ void qhprep_kernel(const float* __restrict__ qh, u16* __restrict__ qhB)
{
    int b = blockIdx.x;
    int t = threadIdx.x;     // 512
    int ns = t >> 6;
    int lane = t & 63;
    int n = ns >> 2, s = ns & 3;
    int q = n * 16 + (lane & 15);
    int kb = s * 32 + (lane >> 4) * 8;
    bf16x8 f;
#pragma unroll
    for (int j = 0; j < 8; ++j) {
        int k = kb + j;
        float v = (q < Q && k < D) ? qh[((size_t)b * Q + q) * D + k] : 0.f;
        f[j] = f2bf(v);
    }
    *reinterpret_cast<bf16x8*>(qhB + ((size_t)(b * 8 + ns) * 64 + lane) * 8) = f;
}

// ========== MFMA Wf: sim -> softmax(q) -> wt=exp(Wf) + e2fsm atomic ==========
__global__ __launch_bounds__(256, 2) void wfm_kernel(const u16* __restrict__ REL,
                                                     const int* __restrict__ frel,
                                                     const u16* __restrict__ qhB,
                                                     const int* __restrict__ headAbs,
                                                     float* __restrict__ wt,
                                                     float* __restrict__ e2fsm, int nrows)
{
    const int lane = threadIdx.x & 63;
    const int lrow = lane & 15, lkg = lane >> 4;
    const int wv = blockIdx.x * (blockDim.x >> 6) + (threadIdx.x >> 6);
    const int nwv = gridDim.x * (blockDim.x >> 6);
    const int nch = nrows >> 4;

    for (int chunk = wv; chunk < nch; chunk += nwv) {
        const int row = chunk * 16 + lrow;
        const int b = (chunk * 16) / F;
        bf16x8 af[4];
        {
            const u16* src = REL + (size_t)frel[row] * SK;
#pragma unroll
            for (int s = 0; s < 4; ++s)
                af[s] = *reinterpret_cast<const bf16x8*>(src + s * 32 + lkg * 8);
        }
        f32x4 acc[2];
        acc[0] = (f32x4){0.f, 0.f, 0.f, 0.f};
        acc[1] = (f32x4){0.f, 0.f, 0.f, 0.f};
#pragma unroll
        for (int s = 0; s < 4; ++s) {
#pragma unroll
            for (int n = 0; n < 2; ++n) {
                bf16x8 qb = *reinterpret_cast<const bf16x8*>(
                    qhB + ((size_t)(b * 8 + n * 4 + s) * 64 + lane) * 8);
                acc[n] = __builtin_amdgcn_mfma_f32_16x16x32_bf16(af[s], qb, acc[n], 0, 0, 0);
            }
        }
        const bool v1 = lrow < (Q - 16);
#pragma unroll
        for (int r = 0; r < 4; ++r) {
            float s0 = acc[0][r] * 0.1f;
            float s1 = acc[1][r] * 0.1f;
            float m = v1 ? fmaxf(s0, s1) : s0;
#pragma unroll
            for (int d = 1; d < 16; d <<= 1) m = fmaxf(m, __shfl_xor(m, d));
            float e0 = __expf(s0 - m);
            float e1 = v1 ? __expf(s1 - m) : 0.f;
            float sum = e0 + e1;
            float wsum = fmaf(e0, s0, e1 * s1);
#pragma unroll
            for (int d = 1; d < 16; d <<= 1) {
                sum += __shfl_xor(sum, d);
                wsum += __shfl_xor(wsum, d);
            }
            if (lrow == 0) {
                int orow = chunk * 16 + lkg * 4 + r;
                float wtl = __expf(wsum / sum);      // no max-shift: cancels in wt/e2fsm
                wt[orow] = wtl;
                atomicAdd(&e2fsm[headAbs[orow]], wtl);
            }
        }
    }
}

// ====== pipelined double-gather mm, XCD-partitioned ======
// e2fS = relu(REL[srel]@W1^T + emb[shead]@W2^T + b1+b2)*rsv ; facts tail-sorted by (b,ent):
// group g = blockIdx.x&7 handles fact chunks [g*nch/8,(g+1)*nch/8) = 2 batches -> per-XCD L2
// working set ~2.5 MB (2x512KB embO slice + 1.5MB REL) < 4MB.
__global__ __launch_bounds__(256, 2) void mm2pipe(
    const u16* __restrict__ RELp, const int* __restrict__ srel,
    const u16* __restrict__ embp, const int* __restrict__ shead,
    const u16* __restrict__ WF1, const u16* __restrict__ WF2,
    const float* __restrict__ b1, const float* __restrict__ b2,
    const float* __restrict__ wtv, const float* __restrict__ prv,
    u16* __restrict__ outp, int nrows)
{
    __shared__ __align__(16) u16 stage[4][16][SST];
    const int lane = threadIdx.x & 63;
    const int lrow = lane & 15, lkg = lane >> 4;
    const int wslot = threadIdx.x >> 6;
    const int nch = (nrows + 15) >> 4;

    const int g = blockIdx.x & 7;
    const int lb = blockIdx.x >> 3;
    const int nchg = nch >> 3;
    const int cbase = g * nchg;
    const int wvg = lb * 4 + wslot;
    const int nwvg = 64 * 4;

    bf16x8 w1[7][4];
#pragma unroll
    for (int n = 0; n < 7; ++n)
#pragma unroll
        for (int s = 0; s < 4; ++s)
            w1[n][s] = *reinterpret_cast<const bf16x8*>(WF1 + ((size_t)(n * 4 + s) * 64 + lane) * 8);

    auto loadA = [&](int ch, bf16x8* f1, bf16x8* f2) {
        int row = ch * 16 + lrow;
        int ar = row < nrows ? row : nrows - 1;
        const u16* s1p = RELp + (size_t)srel[ar] * SK;
        const u16* s2p = embp + (size_t)shead[ar] * SK;
#pragma unroll
        for (int s = 0; s < 4; ++s) {
            f1[s] = *reinterpret_cast<const bf16x8*>(s1p + s * 32 + lkg * 8);
            f2[s] = *reinterpret_cast<const bf16x8*>(s2p + s * 32 + lkg * 8);
        }
    };

    int chunk = cbase + wvg;
    const int cend = cbase + nchg;
    if (chunk >= cend) return;
    bf16x8 cf1[4], cf2[4];
    loadA(chunk, cf1, cf2);
    while (true) {
        const int nxt = chunk + nwvg;
        const bool more = nxt < cend;
        bf16x8 nf1[4], nf2[4];
        if (more) loadA(nxt, nf1, nf2);   // prefetch overlaps MFMA+epilogue below

        f32x4 acc[7];
#pragma unroll
        for (int n = 0; n < 7; ++n) acc[n] = (f32x4){0.f, 0.f, 0.f, 0.f};
#pragma unroll
        for (int s = 0; s < 4; ++s) {
#pragma unroll
            for (int n = 0; n < 7; ++n)
                acc[n] = __builtin_amdgcn_mfma_f32_16x16x32_bf16(cf1[s], w1[n][s], acc[n], 0, 0, 0);
#pragma unroll
            for (int n = 0; n < 7; ++n) {
                bf16x8 w2 = *reinterpret_cast<const bf16x8*>(
                    WF2 + ((size_t)(n * 4 + s) * 64 + lane) * 8);
                acc[n] = __builtin_amdgcn_mfma_f32_16x16x32_bf16(cf2[s], w2, acc[n], 0, 0, 0);
            }
        }

        // epilogue: +b1+b2, relu, *wtv[r]*prv[shead[r]] ; wide stores via LDS stage
        const int rb = chunk * 16 + lkg * 4;
#pragma unroll
        for (int r = 0; r < 4; ++r) {
            const int orow = rb + r;
            const int grow = orow < nrows ? orow : nrows - 1;
            const float rsv = wtv[grow] * prv[shead[grow]];
#pragma unroll
            for (int n = 0; n < 7; ++n) {
                const int col = n * 16 + lrow;
                float v = 0.f;
                if (col < D) {
                    v = acc[n][r] + b1[col] + b2[col];
                    v = fmaxf(v, 0.f) * rsv;
                }
                stage[wslot][lkg * 4 + r][col] = (u16)f2bf(v);
            }
        }
#pragma unroll
        for (int idx = lane; idx < 16 * 13; idx += 64) {
            int rr = idx / 13, cc = idx - rr * 13;
            int orow = chunk * 16 + rr;
            bf16x8 v = *reinterpret_cast<const bf16x8*>(&stage[wslot][rr][cc * 8]);
            if (orow < nrows)
                *reinterpret_cast<bf16x8*>(outp + (size_t)orow * SK + cc * 8) = v;
        }

        if (!more) break;
#pragma unroll
        for (int s = 0; s < 4; ++s) { cf1[s] = nf1[s]; cf2[s] = nf2[s]; }
        chunk = nxt;
    }
}

// ================= two-source MFMA row matmul (round-9 baseline) =================
// A1S: 0 bf16 dense SK, 1 bf16 gather idx1, 2 f32 dense lda1
// A2S: 0 none, 1 bf16 gather idx2, 2 CSR-range sum, 3 bf16 dense
// EPI: 0 plain+b1 ; 1 e2f ; 2 f2e ; 3 final-emb ; 4 final-score (b2=score_w, prOld=score_b, sheadv=local_entity)
// PR: fused pagerank (A2S==2 only)
template<int A1S, int A2S, int EPI, bool OUTBF, bool PR>
__global__ __launch_bounds__(256, 2) void mm2(
    const void* __restrict__ A1p, const int* __restrict__ idx1, int lda1,
    const void* __restrict__ A2p, const int* __restrict__ idx2,
    const u16* __restrict__ WF1, const u16* __restrict__ WF2,
    const float* __restrict__ b1, const float* __restrict__ b2,
    const float* __restrict__ vq,
    const float* __restrict__ wtv, const float* __restrict__ prv,
    const int* __restrict__ row_start,
    const float* __restrict__ prOld, const int* __restrict__ sheadv,
    float* __restrict__ prNew,
    void* __restrict__ outp, int nrows)
{
    __shared__ __align__(16) u16 stage[4][16][SST];
    const int lane = threadIdx.x & 63;
    const int lrow = lane & 15, lkg = lane >> 4;
    const int wslot = threadIdx.x >> 6;
    const int wv = blockIdx.x * (blockDim.x >> 6) + wslot;
    const int nwv = gridDim.x * (blockDim.x >> 6);
    const int nch = (nrows + 15) >> 4;

    bf16x8 w1[7][4];
#pragma unroll
    for (int n = 0; n < 7; ++n)
#pragma unroll
        for (int s = 0; s < 4; ++s)
            w1[n][s] = *reinterpret_cast<const bf16x8*>(WF1 + ((size_t)(n * 4 + s) * 64 + lane) * 8);

    for (int chunk = wv; chunk < nch; chunk += nwv) {
        const int row = chunk * 16 + lrow;
        const int ar = row < nrows ? row : nrows - 1;

        // ---- A1 fragments ----
        bf16x8 af1[4];
        if (A1S == 0) {
            const u16* src = (const u16*)A1p + (size_t)ar * SK;
#pragma unroll
            for (int s = 0; s < 4; ++s)
                af1[s] = *reinterpret_cast<const bf16x8*>(src + s * 32 + lkg * 8);
        } else if (A1S == 1) {
            const u16* src = (const u16*)A1p + (size_t)idx1[ar] * SK;
#pragma unroll
            for (int s = 0; s < 4; ++s)
                af1[s] = *reinterpret_cast<const bf16x8*>(src + s * 32 + lkg * 8);
        } else {
            const float* arow = (const float*)A1p + (size_t)ar * lda1;
#pragma unroll
            for (int s = 0; s < 4; ++s) {
                const int k0 = s * 32 + lkg * 8;
                float tv[8];
                if (k0 + 8 <= D) {
                    float4 v0 = *reinterpret_cast<const float4*>(arow + k0);
                    float4 v1 = *reinterpret_cast<const float4*>(arow + k0 + 4);
                    tv[0]=v0.x; tv[1]=v0.y; tv[2]=v0.z; tv[3]=v0.w;
                    tv[4]=v1.x; tv[5]=v1.y; tv[6]=v1.z; tv[7]=v1.w;
                } else {
#pragma unroll
                    for (int j = 0; j < 8; ++j) tv[j] = (k0 + j < D) ? arow[k0 + j] : 0.f;
                }
                bf16x8 f;
#pragma unroll
                for (int j = 0; j < 8; ++j) f[j] = f2bf(tv[j]);
                af1[s] = f;
            }
        }

        int s0 = 0, s1 = 0;
        if (A2S == 2) { s0 = row_start[ar]; s1 = row_start[ar + 1]; }

        bf16x8 af2[4];
        if (A2S == 1) {
            const u16* src = (const u16*)A2p + (size_t)idx2[ar] * SK;
#pragma unroll
            for (int s = 0; s < 4; ++s)
                af2[s] = *reinterpret_cast<const bf16x8*>(src + s * 32 + lkg * 8);
        } else if (A2S == 3) {
            const u16* src = (const u16*)A2p + (size_t)ar * SK;
#pragma unroll
            for (int s = 0; s < 4; ++s)
                af2[s] = *reinterpret_cast<const bf16x8*>(src + s * 32 + lkg * 8);
        }

        f32x4 acc[7];
#pragma unroll
        for (int n = 0; n < 7; ++n) acc[n] = (f32x4){0.f, 0.f, 0.f, 0.f};
#pragma unroll
        for (int s = 0; s < 4; ++s) {
#pragma unroll
            for (int n = 0; n < 7; ++n)
                acc[n] = __builtin_amdgcn_mfma_f32_16x16x32_bf16(af1[s], w1[n][s], acc[n], 0, 0, 0);
            if (A2S == 1 || A2S == 3) {
#pragma unroll
                for (int n = 0; n < 7; ++n) {
                    bf16x8 w2 = *reinterpret_cast<const bf16x8*>(
                        WF2 + ((size_t)(n * 4 + s) * 64 + lane) * 8);
                    acc[n] = __builtin_amdgcn_mfma_f32_16x16x32_bf16(af2[s], w2, acc[n], 0, 0, 0);
                }
            } else if (A2S == 2) {
                float a2f[8];
#pragma unroll
                for (int j = 0; j < 8; ++j) a2f[j] = 0.f;
                for (int i = s0; i < s1; ++i) {   // contiguous (tail-sorted)
                    bf16x8 v = *reinterpret_cast<const bf16x8*>(
                        (const u16*)A2p + (size_t)i * SK + s * 32 + lkg * 8);
#pragma unroll
                    for (int j = 0; j < 8; ++j) a2f[j] += bf2f((u16)v[j]);
                }
                bf16x8 fsum;
#pragma unroll
                for (int j = 0; j < 8; ++j) fsum[j] = f2bf(a2f[j]);
#pragma unroll
                for (int n = 0; n < 7; ++n) {
                    bf16x8 w2 = *reinterpret_cast<const bf16x8*>(
                        WF2 + ((size_t)(n * 4 + s) * 64 + lane) * 8);
                    acc[n] = __builtin_amdgcn_mfma_f32_16x16x32_bf16(fsum, w2, acc[n], 0, 0, 0);
                }
            }
        }
        if (PR && A2S == 2) {
            if (lkg == 0 && row < nrows) {
                float a = 0.f;
                for (int i = s0; i < s1; ++i) a += prOld[sheadv[i]];
                prNew[row] = PAGERANK_LAMBDA * a + (1.0f - PAGERANK_LAMBDA) * prOld[row];
            }
        }

        // ---- epilogue ----  C/D: col = lane&15, row = (lane>>4)*4 + reg
        const int rb = chunk * 16 + lkg * 4;
        const int bb = (chunk * 16) / E;
#pragma unroll
        for (int r = 0; r < 4; ++r) {
            const int orow = rb + r;
            const int grow = orow < nrows ? orow : nrows - 1;
            float rsv = 1.f, cntf = 0.f;
            if (EPI == 1) rsv = wtv[grow] * prv[idx2[grow]];
            if (EPI == 2) cntf = (float)(row_start[grow + 1] - row_start[grow]);
            float scr = 0.f;
#pragma unroll
            for (int n = 0; n < 7; ++n) {
                const int col = n * 16 + lrow;
                float v = 0.f;
                if (col < D) {
                    v = acc[n][r];
                    if (b1) v += b1[col];
                    if (EPI == 1) v += b2[col];
                    if (EPI == 2) v += FACT_SCALE * cntf * b2[col];
                    if (EPI == 3 || EPI == 4) v += vq[bb * D + col];
                    if (EPI != 0) v = fmaxf(v, 0.f);
                    if (EPI == 1) v *= rsv;
                }
                if (EPI == 4) {
                    if (col < D) scr = fmaf(v, b2[col], scr);
                } else if (OUTBF) {
                    stage[wslot][lkg * 4 + r][col] = (u16)f2bf(v);
                } else if (col < D && orow < nrows) {
                    ((float*)outp)[(size_t)orow * D + col] = v;
                }
            }
            if (EPI == 4) {
                scr += __shfl_xor(scr, 1);
                scr += __shfl_xor(scr, 2);
                scr += __shfl_xor(scr, 4);
                scr += __shfl_xor(scr, 8);
                if (lrow == 0 && orow < nrows) {
                    float s = scr + prOld[0] +
                              ((sheadv[orow] != NUM_ENTITY_C) ? 0.f : VERY_NEG);
                    ((float*)outp)[orow] = s;
                }
            }
        }
        if (OUTBF && EPI != 4) {
            // wave-internal LDS transpose -> wide 16B stores (13 x bf16x8 = cols 0..103)
#pragma unroll
            for (int idx = lane; idx < 16 * 13; idx += 64) {
                int rr = idx / 13, cc = idx - rr * 13;
                int orow = chunk * 16 + rr;
                bf16x8 v = *reinterpret_cast<const bf16x8*>(&stage[wslot][rr][cc * 8]);
                if (orow < nrows)
                    *reinterpret_cast<bf16x8*>((u16*)outp + (size_t)orow * SK + cc * 8) = v;
            }
        }
    }
}

// ================= LSTM =================
__global__ __launch_bounds__(512) void gatesx_kernel(
    const int* __restrict__ qtext, const float* __restrict__ wtab,
    const float* __restrict__ wih, const float* __restrict__ bih,
    const float* __restrict__ bhh, float* __restrict__ gx)
{
    int row = blockIdx.x;
    int t = threadIdx.x;
    __shared__ __align__(16) float xs[D];
    if (t < D) xs[t] = wtab[(size_t)qtext[row] * D + t];
    __syncthreads();
    if (t < 4 * D) {
        const float4* w4 = reinterpret_cast<const float4*>(wih + (size_t)t * D);
        const float4* x4 = reinterpret_cast<const float4*>(xs);
        float a0 = 0.f, a1 = 0.f, a2 = 0.f, a3 = 0.f;
#pragma unroll
        for (int k = 0; k < 25; ++k) {
            float4 wv = w4[k]; float4 xv = x4[k];
            a0 = fmaf(wv.x, xv.x, a0); a1 = fmaf(wv.y, xv.y, a1);
            a2 = fmaf(wv.z, xv.z, a2); a3 = fmaf(wv.w, xv.w, a3);
        }
        gx[(size_t)row * (4 * D) + t] = a0 + a1 + a2 + a3 + bih[t] + bhh[t];
    }
}

__global__ __launch_bounds__(512) void lstmrec_kernel(
    const float* __restrict__ gx, const float* __restrict__ whh,
    float* __restrict__ q_hidden, float* __restrict__ qne)
{
    int b = blockIdx.x, t = threadIdx.x;
    __shared__ __align__(16) float h[D];
    __shared__ float cst[D];
    __shared__ float g[4 * D];
    float4 w[25];
    if (t < 4 * D) {
        const float4* wr = reinterpret_cast<const float4*>(whh + (size_t)t * D);
#pragma unroll
        for (int k = 0; k < 25; ++k) w[k] = wr[k];
    }
    if (t < D) { h[t] = 0.f; cst[t] = 0.f; }
    __syncthreads();
    for (int step = 0; step < Q; ++step) {
        if (t < 4 * D) {
            const float4* h4 = reinterpret_cast<const float4*>(h);
            float a0 = 0.f, a1 = 0.f, a2 = 0.f, a3 = 0.f;
#pragma unroll
            for (int k = 0; k < 25; ++k) {
                float4 hv = h4[k];
                a0 = fmaf(w[k].x, hv.x, a0); a1 = fmaf(w[k].y, hv.y, a1);
                a2 = fmaf(w[k].z, hv.z, a2); a3 = fmaf(w[k].w, hv.w, a3);
            }
            g[t] = a0 + a1 + a2 + a3 + gx[((size_t)b * Q + step) * (4 * D) + t];
        }
        __syncthreads();
        if (t < D) {
            float gi = g[t], gf = g[t + D], gg = g[t + 2 * D], go = g[t + 3 * D];
            float cn = sigf(gf) * cst[t] + sigf(gi) * tanhf(gg);
            float hn = sigf(go) * tanhf(cn);
            cst[t] = cn; h[t] = hn;
            q_hidden[((size_t)b * Q + step) * D + t] = hn;
            if (step == Q - 1) qne[b * D + t] = hn;
        }
        __syncthreads();
    }
}

// ================= small helpers =================
__global__ void idxabs_kernel(const int* __restrict__ kb_head, const int* __restrict__ kb_tail,
                              int* __restrict__ headAbs, int* __restrict__ tailAbs,
                              int* __restrict__ counts)
{
    int r = blockIdx.x * 256 + threadIdx.x;
    if (r < B * F) {
        int b = r / F;
        headAbs[r] = b * E + kb_head[r];
        int t = b * E + kb_tail[r];
        tailAbs[r] = t;
        atomicAdd(&counts[t], 1);
    }
}

__global__ __launch_bounds__(1024) void scan_kernel(const int* __restrict__ counts,
                                                    int* __restrict__ row_start,
                                                    int* __restrict__ cursor)
{
    __shared__ int part[1024];
    int t = threadIdx.x;
    int base = t * 32;
    int local[32];
    int s = 0;
#pragma unroll
    for (int i = 0; i < 32; ++i) {
        int idx = base + i;
        int v = (idx < B * E) ? counts[idx] : 0;
        local[i] = s; s += v;
    }
    part[t] = s;
    __syncthreads();
    for (int off = 1; off < 1024; off <<= 1) {
        int v = (t >= off) ? part[t - off] : 0;
        __syncthreads();
        if (t >= off) part[t] += v;
        __syncthreads();
    }
    int prev = (t > 0) ? part[t - 1] : 0;
#pragma unroll
    for (int i = 0; i < 32; ++i) {
        int idx = base + i;
        if (idx < B * E) { int rs = prev + local[i]; row_start[idx] = rs; cursor[idx] = rs; }
    }
    if (t == 1023) row_start[B * E] = part[1023];
}

// fill + sorted-metadata in one pass (needs wt/e2fsm ready)
__global__ void fillsprep_kernel(const int* __restrict__ tailAbs, int* __restrict__ cursor,
                                 const int* __restrict__ headAbs, const int* __restrict__ frel,
                                 const float* __restrict__ wt, const float* __restrict__ e2fsm,
                                 int* __restrict__ srel, int* __restrict__ shead,
                                 float* __restrict__ srsv)
{
    int r = blockIdx.x * 256 + threadIdx.x;
    if (r < B * F) {
        int p = atomicAdd(&cursor[tailAbs[r]], 1);
        int h = headAbs[r];
        srel[p] = frel[r];
        shead[p] = h;
        srsv[p] = wt[r] / fmaxf(e2fsm[h], VERY_SMALL);
    }
}

__global__ void entgather_kernel(const int* __restrict__ local_entity,
                                 const float* __restrict__ etab, u16* __restrict__ emb,
                                 const float* __restrict__ q2e_adj, float* __restrict__ pr)
{
    int i = blockIdx.x * 256 + threadIdx.x;
    if (i < B * E) pr[i] = q2e_adj[i];
    if (i < B * E * 25) {
        int row = i / 25, p = i - row * 25;
        float4 v = reinterpret_cast<const float4*>(etab + (size_t)local_entity[row] * D)[p];
        short4 o;
        o.x = f2bf(v.x); o.y = f2bf(v.y); o.z = f2bf(v.z); o.w = f2bf(v.w);
        *reinterpret_cast<short4*>(emb + (size_t)row * SK + p * 4) = o;
    }
}

// [optional qne from z] -> q2e_vec -> vq ; clears z for next accumulation
template<bool HASQNE>
__global__ void qvec_kernel(const float* __restrict__ qneIn, float* __restrict__ z,
                            const float* __restrict__ e2qw, const float* __restrict__ e2qb,
                            const float* __restrict__ q2ew, const float* __restrict__ q2eb,
                            const float* __restrict__ e2ew,
                            float* __restrict__ q2e_vec, float* __restrict__ vq)
{
    int b = blockIdx.x, t = threadIdx.x;   // 128 threads
    __shared__ float qn[D];
    __shared__ float qv[D];
    __shared__ float zb[201];
    float* zg = z + b * 201;
    if (HASQNE) {
        for (int i = t; i < 201; i += 128) { zb[i] = zg[i]; zg[i] = 0.f; }
        __syncthreads();
        if (t < D) {
            float ps = zb[2 * D];
            const float* wr = e2qw + (size_t)t * 3 * D;
            float acc = ps * e2qb[t];
            for (int k = 0; k < D; ++k) {
                acc = fmaf(zb[k], wr[k], acc);
                acc = fmaf(ps * q2e_vec[b * D + k], wr[D + k], acc);
                acc = fmaf(zb[D + k], wr[2 * D + k], acc);
            }
            qn[t] = acc;
        }
    } else {
        for (int i = t; i < 201; i += 128) zg[i] = 0.f;
        if (t < D) qn[t] = qneIn[b * D + t];
    }
    __syncthreads();
    if (t < D) {
        const float* wr = q2ew + (size_t)t * D;
        float acc = q2eb[t];
        for (int k = 0; k < D; ++k) acc = fmaf(qn[k], wr[k], acc);
        qv[t] = acc;
    }
    __syncthreads();
    if (t < D) {
        q2e_vec[b * D + t] = qv[t];
        const float* wr = e2ew + (size_t)t * 300 + 100;
        float acc = 0.f;
        for (int k = 0; k < D; ++k) acc = fmaf(qv[k], wr[k], acc);
        vq[b * D + t] = acc;
    }
}

// z per b: [0..99]=sum p*emb, [100..199]=sum p*f2e, [200]=sum p  (atomics; z pre-cleared)
__global__ __launch_bounds__(256) void zsum_kernel(const float* __restrict__ pr,
                                                   const u16* __restrict__ emb,
                                                   const u16* __restrict__ f2e,
                                                   float* __restrict__ z)
{
    const int b = blockIdx.x, ch = blockIdx.y;
    const int t = threadIdx.x;
    const int g = t >> 4, tg = t & 15;
    const int ebase = ch * (E / 16);
    const int eend = ebase + (E / 16);
    float accA[8], accB[8];
#pragma unroll
    for (int j = 0; j < 8; ++j) { accA[j] = 0.f; accB[j] = 0.f; }
    float accp = 0.f;
    for (int e = ebase + g; e < eend; e += 16) {
        const float p = pr[b * E + e];
        const size_t ro = ((size_t)b * E + e) * SK + tg * 8;
        bf16x8 va = *reinterpret_cast<const bf16x8*>(emb + ro);
        bf16x8 vb = *reinterpret_cast<const bf16x8*>(f2e + ro);
#pragma unroll
        for (int j = 0; j < 8; ++j) {
            accA[j] = fmaf(p, bf2f((u16)va[j]), accA[j]);
            accB[j] = fmaf(p, bf2f((u16)vb[j]), accB[j]);
        }
        if (tg == 0) accp += p;
    }
    __shared__ float smA[16][132];
    __shared__ float smB[16][132];
    __shared__ float smp[16];
#pragma unroll
    for (int j = 0; j < 8; ++j) {
        smA[g][tg * 8 + j] = accA[j];
        smB[g][tg * 8 + j] = accB[j];
    }
    if (tg == 0) smp[g] = accp;
    __syncthreads();
    if (t < D) {
        float sa = 0.f, sb = 0.f;
#pragma unroll
        for (int gg = 0; gg < 16; ++gg) { sa += smA[gg][t]; sb += smB[gg][t]; }
        atomicAdd(&z[b * 201 + t], sa);
        atomicAdd(&z[b * 201 + D + t], sb);
    }
    if (t == 255) {
        float sp = 0.f;
#pragma unroll
        for (int gg = 0; gg < 16; ++gg) sp += smp[gg];
        atomicAdd(&z[b * 201 + 2 * D], sp);
    }
}

int mmgrid(int nrows) {      // 4 chunks/wave
    int ch = (nrows + 15) / 16;
    int blocks = (ch + 3) / 4;
    return blocks < 512 ? blocks : 512;
}
int mmgrid2(int nrows) {     // 2 chunks/wave, cap 1024
    int ch = (nrows + 15) / 16;
    int blocks = (ch + 7) / 8;
    return blocks < 1024 ? blocks : 1024;
}

}  // namespace

extern "C" void kernel_launch(void* const* d_in, const int* in_sizes, int n_in,
                              void* d_out, int out_size, void* d_ws, size_t ws_size,
                              hipStream_t stream)
{
    (void)in_sizes; (void)n_in; (void)out_size;
    const int*   local_entity = (const int*)d_in[0];
    const int*   kb_fact_rel  = (const int*)d_in[1];
    const int*   kb_head      = (const int*)d_in[2];
    const int*   kb_tail      = (const int*)d_in[3];
    const int*   query_text   = (const int*)d_in[4];
    const float* q2e_adj      = (const float*)d_in[5];
    const float* entity_table = (const float*)d_in[6];
    const float* rel_table    = (const float*)d_in[7];
    const float* word_table   = (const float*)d_in[8];
    const float* rel_lin_w    = (const float*)d_in[9];
    const float* rel_lin_b    = (const float*)d_in[10];
    const float* lstm_wih     = (const float*)d_in[11];
    const float* lstm_whh     = (const float*)d_in[12];
    const float* lstm_bih     = (const float*)d_in[13];
    const float* lstm_bhh     = (const float*)d_in[14];
    const float* q2e_w        = (const float*)d_in[15];
    const float* q2e_b        = (const float*)d_in[16];
    const float* e2q_w        = (const float*)d_in[17];
    const float* e2q_b        = (const float*)d_in[18];
    const float* e2e_w        = (const float*)d_in[19];
    const float* e2e_b        = (const float*)d_in[20];
    const float* head_w       = (const float*)d_in[21];
    const float* head_b       = (const float*)d_in[22];
    const float* tail_w       = (const float*)d_in[23];
    const float* tail_b       = (const float*)d_in[24];
    const float* self_w       = (const float*)d_in[25];
    const float* self_b       = (const float*)d_in[26];
    const float* score_w      = (const float*)d_in[27];
    const float* score_b      = (const float*)d_in[28];
    float* out = (float*)d_out;

    float* ws = (float*)d_ws;
    size_t o = 0;
    auto alloc = [&](size_t n) { float* p = ws + o; o += (n + 3) & ~(size_t)3; return p; };
    float* q_hidden = alloc((size_t)B * Q * D);
    float* qne      = alloc(B * D);
    float* gx       = alloc((size_t)B * Q * 4 * D);
    float* wt       = alloc((size_t)B * F);
    float* e2fsm    = alloc(B * E);      // adjacent to counts: single memset
    int*   counts   = (int*)alloc(B * E);
    float* pr0      = alloc(B * E);
    float* pr1      = alloc(B * E);
    float* q2e_vec  = alloc(B * D);
    float* vq       = alloc(B * D);
    float* z        = alloc(B * 201);
    float* srsv     = alloc((size_t)B * F);
    u16* WF   = (u16*)alloc((size_t)16 * WFSZ / 2);
    u16* qhB  = (u16*)alloc((size_t)B * 8 * 64 * 8 / 2);
    u16* REL  = (u16*)alloc((size_t)NREL1 * SK / 2 + 64);
    u16* emb0 = (u16*)alloc((size_t)B * E * SK / 2);
    u16* emb1 = (u16*)alloc((size_t)B * E * SK / 2);
    u16* e2fS = (u16*)alloc((size_t)B * F * SK / 2);
    u16* f2e  = (u16*)alloc((size_t)B * E * SK / 2);
    int* headAbs  = (int*)alloc((size_t)B * F);
    int* tailAbs  = (int*)alloc((size_t)B * F);
    int* row_start= (int*)alloc(B * E + 1);
    int* cursor   = (int*)alloc(B * E);
    int* srel     = (int*)alloc((size_t)B * F);
    int* shead    = (int*)alloc((size_t)B * F);
    if (ws_size < o * sizeof(float)) return;

    auto WFm = [&](int m) { return WF + (size_t)m * WFSZ; };

    // ---- prep: weights, LSTM, CSR, REL, attention ----
    wprep_kernel<<<dim3(28, 16), dim3(64), 0, stream>>>(rel_lin_w, self_w, head_w, tail_w,
                                                        e2e_w, WF);
    gatesx_kernel<<<dim3(B * Q), dim3(512), 0, stream>>>(query_text, word_table, lstm_wih,
                                                         lstm_bih, lstm_bhh, gx);
    lstmrec_kernel<<<dim3(B), dim3(512), 0, stream>>>(gx, lstm_whh, q_hidden, qne);
    qhprep_kernel<<<dim3(B), dim3(512), 0, stream>>>(q_hidden, qhB);
    hipMemsetAsync(e2fsm, 0, (size_t)2 * B * E * sizeof(float), stream);  // e2fsm + counts
    idxabs_kernel<<<dim3((B * F + 255) / 256), dim3(256), 0, stream>>>(
        kb_head, kb_tail, headAbs, tailAbs, counts);
    scan_kernel<<<dim3(1), dim3(1024), 0, stream>>>(counts, row_start, cursor);
    mm2<2, 0, 0, true, false><<<dim3(mmgrid(NREL1)), dim3(256), 0, stream>>>(
        rel_table, nullptr, D, nullptr, nullptr, WFm(0), nullptr, rel_lin_b, nullptr,
        nullptr, nullptr, nullptr, nullptr, nullptr, nullptr, nullptr,
        REL, NREL1);
    wfm_kernel<<<dim3(mmgrid2(B * F)), dim3(256), 0, stream>>>(
        REL, kb_fact_rel, qhB, headAbs, wt, e2fsm, B * F);
    fillsprep_kernel<<<dim3((B * F + 255) / 256), dim3(256), 0, stream>>>(
        tailAbs, cursor, headAbs, kb_fact_rel, wt, e2fsm, srel, shead, srsv);
    entgather_kernel<<<dim3((B * E * 25 + 255) / 256), dim3(256), 0, stream>>>(
        local_entity, entity_table, emb0, q2e_adj, pr0);

    u16* embO = emb0; u16* embN = emb1;
    float* prO = pr0; float* prN = pr1;
    for (int i = 0; i < NLAYER; ++i) {
        const float* q2e_wi  = q2e_w + (size_t)i * D * D;
        const float* q2e_bi  = q2e_b + i * D;
        const float* e2e_wi  = e2e_w + (size_t)i * D * 3 * D;
        const float* e2e_bi  = e2e_b + i * D;
        const float* head_bi = head_b + i * D;
        const float* tail_bi = tail_b + i * D;
        const float* self_bi = self_b + i * D;
        const u16* wf_self = WFm(1 + i * 5 + 0);
        const u16* wf_head = WFm(1 + i * 5 + 1);
        const u16* wf_tail = WFm(1 + i * 5 + 2);
        const u16* wf_e2e0 = WFm(1 + i * 5 + 3);
        const u16* wf_e2e2 = WFm(1 + i * 5 + 4);
        const bool last = (i == NLAYER - 1);

        if (i == 0)
            qvec_kernel<false><<<dim3(B), dim3(128), 0, stream>>>(
                qne, z, nullptr, nullptr, q2e_wi, q2e_bi, e2e_wi, q2e_vec, vq);
        else
            qvec_kernel<true><<<dim3(B), dim3(128), 0, stream>>>(
                nullptr, z, e2q_w + (size_t)(i - 1) * D * 3 * D, e2q_b + (size_t)(i - 1) * D,
                q2e_wi, q2e_bi, e2e_wi, q2e_vec, vq);

        // e2fS[p] = relu(REL[srel]@self^T + embO[shead]@head^T + biases) * srsv * prO[shead]
        mm2pipe<<<dim3(512), dim3(256), 0, stream>>>(
            REL, srel, embO, shead, wf_self, wf_head, self_bi, head_bi,
            srsv, prO, e2fS, B * F);
        // f2e = relu(embO@self^T + b + FS*(rangesum(e2fS)@tail^T + cnt*b2)); prN fused (L1-2)
        if (!last)
            mm2<0, 2, 2, true, true><<<dim3(mmgrid(B * E)), dim3(256), 0, stream>>>(
                embO, nullptr, 0, e2fS, nullptr, wf_self, wf_tail, self_bi, tail_bi,
                nullptr, nullptr, nullptr, row_start, prO, shead, prN,
                f2e, B * E);
        else
            mm2<0, 2, 2, true, false><<<dim3(mmgrid(B * E)), dim3(256), 0, stream>>>(
                embO, nullptr, 0, e2fS, nullptr, wf_self, wf_tail, self_bi, tail_bi,
                nullptr, nullptr, nullptr, row_start, nullptr, nullptr, nullptr,
                f2e, B * E);
        if (!last)
            zsum_kernel<<<dim3(B, 16), dim3(256), 0, stream>>>(prN, embO, f2e, z);
        // final: embN (L1-2) or score directly (L3)
        if (!last)
            mm2<0, 3, 3, true, false><<<dim3(mmgrid(B * E)), dim3(256), 0, stream>>>(
                embO, nullptr, 0, f2e, nullptr, wf_e2e0, wf_e2e2, e2e_bi, nullptr,
                vq, nullptr, nullptr, nullptr, nullptr, nullptr, nullptr,
                embN, B * E);
        else
            mm2<0, 3, 4, false, false><<<dim3(mmgrid(B * E)), dim3(256), 0, stream>>>(
                embO, nullptr, 0, f2e, nullptr, wf_e2e0, wf_e2e2, e2e_bi, score_w,
                vq, nullptr, nullptr, nullptr, score_b, local_entity, nullptr,
                out, B * E);
        { u16* tmp = embO; embO = embN; embN = tmp; }
        { float* tmp = prO; prO = prN; prN = tmp; }
    }
}